// Round 2
// baseline (1799.201 us; speedup 1.0000x reference)
//
#include <hip/hip_runtime.h>
#include <hip/hip_bf16.h>
#include <cstdint>

#define B_  8
#define T_  1024
#define C_  768
#define H_  12
#define DH_ 64

// ---------------------------------------------------------------------------
// Tiled fp32 GEMM, BM=BN=64, BK=16, 256 threads, 4x4 per thread.
// A is [M, 768] row-major. Two variants differ in B layout + epilogue.
// ---------------------------------------------------------------------------

__global__ __launch_bounds__(256) void qkv_gemm(
        const float* __restrict__ x,
        const float* __restrict__ Wq, const float* __restrict__ Wk,
        const float* __restrict__ Wv,
        float* __restrict__ qb, float* __restrict__ kb, float* __restrict__ vb)
{
    const int K = C_;
    const float* W   = (blockIdx.z == 0) ? Wq : ((blockIdx.z == 1) ? Wk : Wv);
    float*       out = (blockIdx.z == 0) ? qb : ((blockIdx.z == 1) ? kb : vb);

    const int m0 = blockIdx.y * 64;
    const int n0 = blockIdx.x * 64;      // aligned to a head boundary
    const int h  = n0 >> 6;
    const float* Wh = W + (size_t)h * K * DH_;   // [K][64] row-major

    __shared__ float As[16][66];   // transposed A tile, padded
    __shared__ float Bs[16][64];

    const int tid = threadIdx.x;
    const int tx  = tid & 15, ty = tid >> 4;

    float acc[4][4] = {};

    for (int k0 = 0; k0 < K; k0 += 16) {
        // A tile 64x16 -> As[k][m]
        {
            const int row = tid >> 2;          // 0..63
            const int c4  = (tid & 3) * 4;     // 0,4,8,12
            const float4 a = *(const float4*)(x + (size_t)(m0 + row) * K + k0 + c4);
            As[c4 + 0][row] = a.x; As[c4 + 1][row] = a.y;
            As[c4 + 2][row] = a.z; As[c4 + 3][row] = a.w;
        }
        // B tile 16x64 (contiguous in d within the head)
        {
            const int brow = tid >> 4;         // 0..15
            const int bc4  = (tid & 15) * 4;   // 0..60
            *(float4*)(&Bs[brow][bc4]) =
                *(const float4*)(Wh + (size_t)(k0 + brow) * DH_ + bc4);
        }
        __syncthreads();
        #pragma unroll
        for (int kk = 0; kk < 16; ++kk) {
            float a[4];
            #pragma unroll
            for (int i = 0; i < 4; ++i) a[i] = As[kk][ty * 4 + i];
            const float4 bv = *(const float4*)(&Bs[kk][tx * 4]);
            const float bb[4] = {bv.x, bv.y, bv.z, bv.w};
            #pragma unroll
            for (int i = 0; i < 4; ++i)
                #pragma unroll
                for (int j = 0; j < 4; ++j) acc[i][j] += a[i] * bb[j];
        }
        __syncthreads();
    }
    #pragma unroll
    for (int i = 0; i < 4; ++i) {
        const int m = m0 + ty * 4 + i;
        float4 r = make_float4(acc[i][0], acc[i][1], acc[i][2], acc[i][3]);
        *(float4*)(out + (size_t)m * C_ + n0 + tx * 4) = r;
    }
}

__global__ __launch_bounds__(256) void proj_gemm(
        const float* __restrict__ A,      // [8192, 768] attn output
        const float* __restrict__ Wp,     // [768, 768] row-major
        const float* __restrict__ bp,     // [768]
        float* __restrict__ out)
{
    const int K = C_;
    const int m0 = blockIdx.y * 64;
    const int n0 = blockIdx.x * 64;

    __shared__ float As[16][66];
    __shared__ float Bs[16][64];

    const int tid = threadIdx.x;
    const int tx  = tid & 15, ty = tid >> 4;

    float acc[4][4] = {};

    for (int k0 = 0; k0 < K; k0 += 16) {
        {
            const int row = tid >> 2;
            const int c4  = (tid & 3) * 4;
            const float4 a = *(const float4*)(A + (size_t)(m0 + row) * K + k0 + c4);
            As[c4 + 0][row] = a.x; As[c4 + 1][row] = a.y;
            As[c4 + 2][row] = a.z; As[c4 + 3][row] = a.w;
        }
        {
            const int brow = tid >> 4;
            const int bc4  = (tid & 15) * 4;
            *(float4*)(&Bs[brow][bc4]) =
                *(const float4*)(Wp + (size_t)(k0 + brow) * C_ + n0 + bc4);
        }
        __syncthreads();
        #pragma unroll
        for (int kk = 0; kk < 16; ++kk) {
            float a[4];
            #pragma unroll
            for (int i = 0; i < 4; ++i) a[i] = As[kk][ty * 4 + i];
            const float4 bv = *(const float4*)(&Bs[kk][tx * 4]);
            const float bb[4] = {bv.x, bv.y, bv.z, bv.w};
            #pragma unroll
            for (int i = 0; i < 4; ++i)
                #pragma unroll
                for (int j = 0; j < 4; ++j) acc[i][j] += a[i] * bb[j];
        }
        __syncthreads();
    }
    #pragma unroll
    for (int i = 0; i < 4; ++i) {
        const int m = m0 + ty * 4 + i;
        float4 r = make_float4(acc[i][0] + bp[n0 + tx * 4 + 0],
                               acc[i][1] + bp[n0 + tx * 4 + 1],
                               acc[i][2] + bp[n0 + tx * 4 + 2],
                               acc[i][3] + bp[n0 + tx * 4 + 3]);
        *(float4*)(out + (size_t)m * C_ + n0 + tx * 4) = r;
    }
}

// ---------------------------------------------------------------------------
// Flash-style causal attention, fp32. Block = 256 threads handles one
// (b, h, 16 q-rows). Thread mapping (r, c): r = tid>>4 is the q-row,
// c = tid&15 is the score column (phase 1) / d-group of 4 (phase 2).
// q/k/v live in [B,T,H*D] layout (column slice per head).
// ---------------------------------------------------------------------------

__global__ __launch_bounds__(256) void attn_kernel(
        const float* __restrict__ qb, const float* __restrict__ kb,
        const float* __restrict__ vb, float* __restrict__ ob)
{
    const int t0 = blockIdx.x * 16;
    const int h  = blockIdx.y;
    const int b  = blockIdx.z;
    const int tid = threadIdx.x;
    const int r = tid >> 4;
    const int c = tid & 15;

    __shared__ float q_s[16][65];
    __shared__ float k_s[16][65];
    __shared__ float v_s[16][65];
    __shared__ float p_s[16][17];

    // load q tile, fold in the 1/sqrt(D) scale
    {
        const int row = tid >> 4;
        const int c4  = (tid & 15) * 4;
        const float4 qv = *(const float4*)(qb + ((size_t)(b * T_ + t0 + row)) * C_ + h * DH_ + c4);
        q_s[row][c4 + 0] = qv.x * 0.125f;
        q_s[row][c4 + 1] = qv.y * 0.125f;
        q_s[row][c4 + 2] = qv.z * 0.125f;
        q_s[row][c4 + 3] = qv.w * 0.125f;
    }

    float m = -1e30f, l = 0.0f;
    float acc[4] = {0.f, 0.f, 0.f, 0.f};

    const int ntiles = blockIdx.x + 1;   // s tiles 0 .. t0/16
    for (int st = 0; st < ntiles; ++st) {
        const int s0 = st * 16;
        __syncthreads();   // prior iteration done with k_s/v_s/p_s
        {
            const int row = tid >> 4;
            const int c4  = (tid & 15) * 4;
            const float4 k4 = *(const float4*)(kb + ((size_t)(b * T_ + s0 + row)) * C_ + h * DH_ + c4);
            k_s[row][c4 + 0] = k4.x; k_s[row][c4 + 1] = k4.y;
            k_s[row][c4 + 2] = k4.z; k_s[row][c4 + 3] = k4.w;
            const float4 v4 = *(const float4*)(vb + ((size_t)(b * T_ + s0 + row)) * C_ + h * DH_ + c4);
            v_s[row][c4 + 0] = v4.x; v_s[row][c4 + 1] = v4.y;
            v_s[row][c4 + 2] = v4.z; v_s[row][c4 + 3] = v4.w;
        }
        __syncthreads();

        // scores: thread (r, si=c)
        float sc = 0.0f;
        #pragma unroll
        for (int cc = 0; cc < DH_; ++cc) sc += q_s[r][cc] * k_s[c][cc];
        if (s0 + c > t0 + r) sc = -1e30f;   // causal mask

        // row reductions within the 16 contiguous lanes of this row
        float tm = sc;
        #pragma unroll
        for (int mk = 8; mk >= 1; mk >>= 1) tm = fmaxf(tm, __shfl_xor(tm, mk, 16));
        const float m_new = fmaxf(m, tm);
        const float p = expf(sc - m_new);   // masked -> exp(-huge) == 0
        float ps = p;
        #pragma unroll
        for (int mk = 8; mk >= 1; mk >>= 1) ps += __shfl_xor(ps, mk, 16);
        const float scale = expf(m - m_new);
        l = l * scale + ps;
        m = m_new;
        p_s[r][c] = p;
        __syncthreads();

        // PV: thread (r, dg=c) owns d = c*4 .. c*4+3
        #pragma unroll
        for (int j = 0; j < 4; ++j) acc[j] *= scale;
        #pragma unroll
        for (int s = 0; s < 16; ++s) {
            const float pv = p_s[r][s];
            #pragma unroll
            for (int j = 0; j < 4; ++j) acc[j] += pv * v_s[s][c * 4 + j];
        }
    }

    const float inv_l = 1.0f / l;
    float* op = ob + ((size_t)(b * T_ + t0 + r)) * C_ + h * DH_ + c * 4;
    op[0] = acc[0] * inv_l;
    op[1] = acc[1] * inv_l;
    op[2] = acc[2] * inv_l;
    op[3] = acc[3] * inv_l;
}

// ---------------------------------------------------------------------------

extern "C" void kernel_launch(void* const* d_in, const int* in_sizes, int n_in,
                              void* d_out, int out_size, void* d_ws, size_t ws_size,
                              hipStream_t stream)
{
    const float* x  = (const float*)d_in[0];
    const float* Wq = (const float*)d_in[1];
    const float* Wk = (const float*)d_in[2];
    const float* Wv = (const float*)d_in[3];
    const float* Wp = (const float*)d_in[4];
    const float* bp = (const float*)d_in[5];
    float* out = (float*)d_out;

    float* ws = (float*)d_ws;
    const size_t MK = (size_t)B_ * T_ * C_;   // 6,291,456 floats
    float* qb = ws;
    float* kb = ws + MK;
    float* vb = ws + 2 * MK;
    float* ab = ws + 3 * MK;

    // 1) QKV projections: [8192,768] x [768,64] per head, q/k/v in [B,T,H*D]
    dim3 gq(C_ / 64, (B_ * T_) / 64, 3);
    qkv_gemm<<<gq, dim3(256), 0, stream>>>(x, Wq, Wk, Wv, qb, kb, vb);

    // 2) causal flash attention -> ab in [B,T,H*D]
    dim3 ga(T_ / 16, H_, B_);
    attn_kernel<<<ga, dim3(256), 0, stream>>>(qb, kb, vb, ab);

    // 3) output projection + bias -> d_out
    dim3 gp(C_ / 64, (B_ * T_) / 64);
    proj_gemm<<<gp, dim3(256), 0, stream>>>(ab, Wp, bp, out);
}

// Round 4
// 803.687 us; speedup vs baseline: 2.2387x; 2.2387x over previous
//
#include <hip/hip_runtime.h>
#include <hip/hip_bf16.h>
#include <cstdint>

#define B_  8
#define T_  1024
#define C_  768
#define H_  12
#define DH_ 64

typedef __attribute__((ext_vector_type(8))) short short8v;
typedef __attribute__((ext_vector_type(4))) short short4v;
typedef __attribute__((ext_vector_type(4))) float f32x4;

static __device__ __forceinline__ short f2bf(float x) {
    __hip_bfloat16 h = __float2bfloat16(x);
    return *reinterpret_cast<const short*>(&h);
}

// ---------------------------------------------------------------------------
// QKV projection: fp32 tiled GEMM, epilogue emits bf16 into [B,H,T,64].
// q gets the 1/sqrt(DH)=0.125 scale folded in (power of 2 -> exact in bf16).
// ---------------------------------------------------------------------------

__global__ __launch_bounds__(256) void qkv_gemm(
        const float* __restrict__ x,
        const float* __restrict__ Wq, const float* __restrict__ Wk,
        const float* __restrict__ Wv,
        __hip_bfloat16* __restrict__ qb, __hip_bfloat16* __restrict__ kb,
        __hip_bfloat16* __restrict__ vb)
{
    const int K = C_;
    const float* W = (blockIdx.z == 0) ? Wq : ((blockIdx.z == 1) ? Wk : Wv);
    __hip_bfloat16* out = (blockIdx.z == 0) ? qb : ((blockIdx.z == 1) ? kb : vb);
    const float osc = (blockIdx.z == 0) ? 0.125f : 1.0f;

    const int m0 = blockIdx.y * 64;
    const int n0 = blockIdx.x * 64;      // head boundary
    const int h  = n0 >> 6;
    const float* Wh = W + (size_t)h * K * DH_;   // [K][64] row-major

    __shared__ float As[16][66];
    __shared__ float Bs[16][64];

    const int tid = threadIdx.x;
    const int tx  = tid & 15, ty = tid >> 4;

    float acc[4][4] = {};

    for (int k0 = 0; k0 < K; k0 += 16) {
        {
            const int row = tid >> 2;
            const int c4  = (tid & 3) * 4;
            const float4 a = *(const float4*)(x + (size_t)(m0 + row) * K + k0 + c4);
            As[c4 + 0][row] = a.x; As[c4 + 1][row] = a.y;
            As[c4 + 2][row] = a.z; As[c4 + 3][row] = a.w;
        }
        {
            const int brow = tid >> 4;
            const int bc4  = (tid & 15) * 4;
            *(float4*)(&Bs[brow][bc4]) =
                *(const float4*)(Wh + (size_t)(k0 + brow) * DH_ + bc4);
        }
        __syncthreads();
        #pragma unroll
        for (int kk = 0; kk < 16; ++kk) {
            float a[4];
            #pragma unroll
            for (int i = 0; i < 4; ++i) a[i] = As[kk][ty * 4 + i];
            const float4 bv = *(const float4*)(&Bs[kk][tx * 4]);
            const float bb[4] = {bv.x, bv.y, bv.z, bv.w};
            #pragma unroll
            for (int i = 0; i < 4; ++i)
                #pragma unroll
                for (int j = 0; j < 4; ++j) acc[i][j] += a[i] * bb[j];
        }
        __syncthreads();
    }
    #pragma unroll
    for (int i = 0; i < 4; ++i) {
        const int m  = m0 + ty * 4 + i;
        const int bb_ = m >> 10;          // T_ = 1024
        const int tt  = m & (T_ - 1);
        short4v r;
        r.x = f2bf(acc[i][0] * osc); r.y = f2bf(acc[i][1] * osc);
        r.z = f2bf(acc[i][2] * osc); r.w = f2bf(acc[i][3] * osc);
        short* op = (short*)out + (((size_t)(bb_ * H_ + h)) * T_ + tt) * 64 + tx * 4;
        *(short4v*)op = r;
    }
}

// ---------------------------------------------------------------------------
// V transpose per head: [B,H,T,64] -> [B,H,64,T] (bf16), 64x64 tiles.
// ---------------------------------------------------------------------------

__global__ __launch_bounds__(256) void v_transpose(
        const __hip_bfloat16* __restrict__ vb, __hip_bfloat16* __restrict__ vt)
{
    const int t0 = blockIdx.x * 64;
    const int h  = blockIdx.y;
    const int b  = blockIdx.z;
    __shared__ short tile[64][72];
    const int tid = threadIdx.x;
    const int r   = tid >> 2;        // 0..63
    const int seg = tid & 3;         // 0..3 (16 elems each)

    const short* src = (const short*)vb +
        (((size_t)(b * H_ + h)) * T_ + t0 + r) * 64 + seg * 16;
    *(short8v*)(&tile[r][seg * 16])     = *(const short8v*)(src);
    *(short8v*)(&tile[r][seg * 16 + 8]) = *(const short8v*)(src + 8);
    __syncthreads();

    short* dst = (short*)vt +
        (((size_t)(b * H_ + h)) * 64 + r) * T_ + t0 + seg * 16;
    short8v o0, o1;
    #pragma unroll
    for (int j = 0; j < 8; ++j) o0[j] = tile[seg * 16 + j][r];
    #pragma unroll
    for (int j = 0; j < 8; ++j) o1[j] = tile[seg * 16 + 8 + j][r];
    *(short8v*)(dst)     = o0;
    *(short8v*)(dst + 8) = o1;
}

// ---------------------------------------------------------------------------
// Flash attention, bf16 MFMA. Block = 256 thr = 4 waves, one 64-row q tile
// per block; wave w owns q rows [t0+16w, t0+16w+16). KV tiles of 64.
// q/k: [B,H,T,64] bf16 (q pre-scaled). vt: [B,H,64,T] bf16.
// mfma_f32_16x16x32_bf16: A/B frag = row/col lane%16, k = 8*(lane/16)+j;
// C/D: col = lane&15, row = 4*(lane>>4)+reg  [m89-verified].
// ---------------------------------------------------------------------------

__global__ __launch_bounds__(256) void attn_mfma(
        const __hip_bfloat16* __restrict__ qb,
        const __hip_bfloat16* __restrict__ kb,
        const __hip_bfloat16* __restrict__ vt,
        float* __restrict__ ab)
{
    const int bx = blockIdx.x;
    const int h  = blockIdx.y;
    const int b  = blockIdx.z;
    const int tid = threadIdx.x;
    const int w  = tid >> 6;
    const int l  = tid & 63;
    const int lg = l >> 4;    // 0..3
    const int lc = l & 15;    // 0..15

    const int t0 = bx * 64;
    const int q0 = t0 + w * 16;

    const size_t headRow = ((size_t)(b * H_ + h)) * T_;   // q/k row base
    const size_t vtRow   = ((size_t)(b * H_ + h)) * 64;   // vt row base (d rows)

    // Q fragments (held for the whole kernel)
    short8v aq0, aq1;
    {
        const short* qp = (const short*)qb + (headRow + q0 + lc) * 64 + lg * 8;
        aq0 = *(const short8v*)(qp);
        aq1 = *(const short8v*)(qp + 32);
    }

    __shared__ short p_s[4][16][72];   // per-wave P tile (rows 16B-aligned: 144B)

    float m_r[4], l_r[4];
    f32x4 o_acc[4];
    #pragma unroll
    for (int r = 0; r < 4; ++r) { m_r[r] = -1e30f; l_r[r] = 0.0f; }
    #pragma unroll
    for (int n = 0; n < 4; ++n) o_acc[n] = (f32x4){0.f, 0.f, 0.f, 0.f};

    const int ntiles = bx + 1;   // uniform across all 4 waves
    for (int kt = 0; kt < ntiles; ++kt) {
        const int kv0 = kt * 64;

        // --- scores S[16q][64kv]: 4 n-subtiles x 2 d-halves ---
        f32x4 s[4];
        #pragma unroll
        for (int n = 0; n < 4; ++n) {
            const short* kp = (const short*)kb + (headRow + kv0 + n * 16 + lc) * 64 + lg * 8;
            short8v bk0 = *(const short8v*)(kp);
            short8v bk1 = *(const short8v*)(kp + 32);
            f32x4 acc = (f32x4){0.f, 0.f, 0.f, 0.f};
            acc = __builtin_amdgcn_mfma_f32_16x16x32_bf16(aq0, bk0, acc, 0, 0, 0);
            acc = __builtin_amdgcn_mfma_f32_16x16x32_bf16(aq1, bk1, acc, 0, 0, 0);
            s[n] = acc;
        }

        // --- causal mask (only the diagonal tile) ---
        if (kt == ntiles - 1) {
            #pragma unroll
            for (int n = 0; n < 4; ++n) {
                const int kvg = kv0 + n * 16 + lc;
                #pragma unroll
                for (int r = 0; r < 4; ++r) {
                    const int qg = q0 + lg * 4 + r;
                    if (kvg > qg) s[n][r] = -1e30f;
                }
            }
        }

        // --- online softmax (rows = 4 regs; cols across 16-lane group) ---
        float p[4][4];        // [n][r]
        float pscale[4];
        #pragma unroll
        for (int r = 0; r < 4; ++r) {
            float tm = fmaxf(fmaxf(s[0][r], s[1][r]), fmaxf(s[2][r], s[3][r]));
            #pragma unroll
            for (int mk = 8; mk >= 1; mk >>= 1) tm = fmaxf(tm, __shfl_xor(tm, mk, 16));
            const float mnew = fmaxf(m_r[r], tm);
            pscale[r] = __expf(m_r[r] - mnew);
            float ps = 0.f;
            #pragma unroll
            for (int n = 0; n < 4; ++n) { p[n][r] = __expf(s[n][r] - mnew); ps += p[n][r]; }
            #pragma unroll
            for (int mk = 8; mk >= 1; mk >>= 1) ps += __shfl_xor(ps, mk, 16);
            l_r[r] = l_r[r] * pscale[r] + ps;
            m_r[r] = mnew;
        }
        #pragma unroll
        for (int n = 0; n < 4; ++n)
            #pragma unroll
            for (int r = 0; r < 4; ++r) o_acc[n][r] *= pscale[r];

        // --- P -> LDS (bf16) in A-fragment-friendly row-major [16][64] ---
        #pragma unroll
        for (int n = 0; n < 4; ++n)
            #pragma unroll
            for (int r = 0; r < 4; ++r)
                p_s[w][lg * 4 + r][n * 16 + lc] = f2bf(p[n][r]);
        __syncthreads();

        // --- PV: A = P frags, B = Vt frags (contiguous 16B from global) ---
        const short* prow = &p_s[w][lc][lg * 8];
        short8v pa0 = *(const short8v*)(prow);
        short8v pa1 = *(const short8v*)(prow + 32);
        #pragma unroll
        for (int n = 0; n < 4; ++n) {
            const short* vp = (const short*)vt + (vtRow + n * 16 + lc) * T_ + kv0 + lg * 8;
            short8v bv0 = *(const short8v*)(vp);
            short8v bv1 = *(const short8v*)(vp + 32);
            o_acc[n] = __builtin_amdgcn_mfma_f32_16x16x32_bf16(pa0, bv0, o_acc[n], 0, 0, 0);
            o_acc[n] = __builtin_amdgcn_mfma_f32_16x16x32_bf16(pa1, bv1, o_acc[n], 0, 0, 0);
        }
    }

    // --- normalize + store to ab fp32 [B,T,H*64] ---
    #pragma unroll
    for (int r = 0; r < 4; ++r) {
        const float inv = 1.0f / l_r[r];
        const int q = q0 + lg * 4 + r;
        float* op = ab + ((size_t)(b * T_) + q) * C_ + h * 64 + lc;
        #pragma unroll
        for (int n = 0; n < 4; ++n) op[n * 16] = o_acc[n][r] * inv;
    }
}

// ---------------------------------------------------------------------------
// Output projection: fp32 tiled GEMM + bias (unchanged).
// ---------------------------------------------------------------------------

__global__ __launch_bounds__(256) void proj_gemm(
        const float* __restrict__ A,
        const float* __restrict__ Wp,
        const float* __restrict__ bp,
        float* __restrict__ out)
{
    const int K = C_;
    const int m0 = blockIdx.y * 64;
    const int n0 = blockIdx.x * 64;

    __shared__ float As[16][66];
    __shared__ float Bs[16][64];

    const int tid = threadIdx.x;
    const int tx  = tid & 15, ty = tid >> 4;

    float acc[4][4] = {};

    for (int k0 = 0; k0 < K; k0 += 16) {
        {
            const int row = tid >> 2;
            const int c4  = (tid & 3) * 4;
            const float4 a = *(const float4*)(A + (size_t)(m0 + row) * K + k0 + c4);
            As[c4 + 0][row] = a.x; As[c4 + 1][row] = a.y;
            As[c4 + 2][row] = a.z; As[c4 + 3][row] = a.w;
        }
        {
            const int brow = tid >> 4;
            const int bc4  = (tid & 15) * 4;
            *(float4*)(&Bs[brow][bc4]) =
                *(const float4*)(Wp + (size_t)(k0 + brow) * C_ + n0 + bc4);
        }
        __syncthreads();
        #pragma unroll
        for (int kk = 0; kk < 16; ++kk) {
            float a[4];
            #pragma unroll
            for (int i = 0; i < 4; ++i) a[i] = As[kk][ty * 4 + i];
            const float4 bv = *(const float4*)(&Bs[kk][tx * 4]);
            const float bb[4] = {bv.x, bv.y, bv.z, bv.w};
            #pragma unroll
            for (int i = 0; i < 4; ++i)
                #pragma unroll
                for (int j = 0; j < 4; ++j) acc[i][j] += a[i] * bb[j];
        }
        __syncthreads();
    }
    #pragma unroll
    for (int i = 0; i < 4; ++i) {
        const int m = m0 + ty * 4 + i;
        float4 r = make_float4(acc[i][0] + bp[n0 + tx * 4 + 0],
                               acc[i][1] + bp[n0 + tx * 4 + 1],
                               acc[i][2] + bp[n0 + tx * 4 + 2],
                               acc[i][3] + bp[n0 + tx * 4 + 3]);
        *(float4*)(out + (size_t)m * C_ + n0 + tx * 4) = r;
    }
}

// ---------------------------------------------------------------------------

extern "C" void kernel_launch(void* const* d_in, const int* in_sizes, int n_in,
                              void* d_out, int out_size, void* d_ws, size_t ws_size,
                              hipStream_t stream)
{
    const float* x  = (const float*)d_in[0];
    const float* Wq = (const float*)d_in[1];
    const float* Wk = (const float*)d_in[2];
    const float* Wv = (const float*)d_in[3];
    const float* Wp = (const float*)d_in[4];
    const float* bp = (const float*)d_in[5];
    float* out = (float*)d_out;

    char* ws = (char*)d_ws;
    const size_t NE  = (size_t)B_ * T_ * C_;        // 6,291,456 elements
    const size_t BF  = NE * sizeof(short);          // 12.58 MB per bf16 buffer
    __hip_bfloat16* qb = (__hip_bfloat16*)(ws);
    __hip_bfloat16* kb = (__hip_bfloat16*)(ws + BF);
    __hip_bfloat16* vb = (__hip_bfloat16*)(ws + 2 * BF);
    __hip_bfloat16* vt = (__hip_bfloat16*)(ws + 3 * BF);
    float*          ab = (float*)         (ws + 4 * BF);

    // 1) QKV projections -> bf16 [B,H,T,64]
    dim3 gq(C_ / 64, (B_ * T_) / 64, 3);
    qkv_gemm<<<gq, dim3(256), 0, stream>>>(x, Wq, Wk, Wv, qb, kb, vb);

    // 2) V transpose -> [B,H,64,T]
    dim3 gt(T_ / 64, H_, B_);
    v_transpose<<<gt, dim3(256), 0, stream>>>(vb, vt);

    // 3) causal flash attention (MFMA) -> ab fp32 [B,T,C]
    dim3 ga(T_ / 64, H_, B_);
    attn_mfma<<<ga, dim3(256), 0, stream>>>(qb, kb, vt, ab);

    // 4) output projection + bias -> d_out
    dim3 gp(C_ / 64, (B_ * T_) / 64);
    proj_gemm<<<gp, dim3(256), 0, stream>>>(ab, Wp, bp, out);
}

// Round 6
// 367.256 us; speedup vs baseline: 4.8990x; 2.1884x over previous
//
#include <hip/hip_runtime.h>
#include <hip/hip_bf16.h>
#include <cstdint>

#define B_  8
#define T_  1024
#define C_  768
#define H_  12
#define DH_ 64

#define BM 128
#define BN 128
#define BK 64

typedef __attribute__((ext_vector_type(8))) short short8v;
typedef __attribute__((ext_vector_type(4))) short short4v;
typedef __attribute__((ext_vector_type(4))) float f32x4;

static __device__ __forceinline__ short f2bf(float x) {
    __hip_bfloat16 h = __float2bfloat16(x);
    return *reinterpret_cast<const short*>(&h);
}

static __device__ __forceinline__ void gload16(const short* g, short* l) {
    __builtin_amdgcn_global_load_lds(
        (const __attribute__((address_space(1))) unsigned int*)g,
        (__attribute__((address_space(3))) unsigned int*)l, 16, 0, 0);
}

// ---------------------------------------------------------------------------
// x fp32 [8192][768] -> bf16 (same layout). 8 elems/thread.
// ---------------------------------------------------------------------------
__global__ __launch_bounds__(256) void x_to_bf16(
        const float* __restrict__ x, short* __restrict__ xb)
{
    const size_t i = ((size_t)blockIdx.x * 256 + threadIdx.x) * 8;
    const float4 a = *(const float4*)(x + i);
    const float4 b = *(const float4*)(x + i + 4);
    short8v o;
    o[0] = f2bf(a.x); o[1] = f2bf(a.y); o[2] = f2bf(a.z); o[3] = f2bf(a.w);
    o[4] = f2bf(b.x); o[5] = f2bf(b.y); o[6] = f2bf(b.z); o[7] = f2bf(b.w);
    *(short8v*)(xb + i) = o;
}

// ---------------------------------------------------------------------------
// Wq/Wk/Wv [H][768][64] fp32 -> wt [3][768][768] bf16, transposed per head:
// wt[z][h*64+d][c] = W[z][h][c][d].  Tiles 64x64, grid (12, 12, 3).
// ---------------------------------------------------------------------------
__global__ __launch_bounds__(256) void w_transpose(
        const float* __restrict__ Wq, const float* __restrict__ Wk,
        const float* __restrict__ Wv, short* __restrict__ wt)
{
    const int z = blockIdx.z;
    const float* W = (z == 0) ? Wq : ((z == 1) ? Wk : Wv);
    short* dst = wt + (size_t)z * C_ * C_;
    const int c0 = blockIdx.x * 64;
    const int h  = blockIdx.y;
    __shared__ float tile[64][65];
    const int tid = threadIdx.x;
    const int r = tid >> 2, seg = tid & 3;

    const float* src = W + ((size_t)h * C_ + c0 + r) * 64 + seg * 16;
    #pragma unroll
    for (int u = 0; u < 4; ++u) {
        const float4 v = *(const float4*)(src + u * 4);
        tile[r][seg * 16 + u * 4 + 0] = v.x;
        tile[r][seg * 16 + u * 4 + 1] = v.y;
        tile[r][seg * 16 + u * 4 + 2] = v.z;
        tile[r][seg * 16 + u * 4 + 3] = v.w;
    }
    __syncthreads();
    short* o = dst + ((size_t)h * 64 + r) * C_ + c0 + seg * 16;
    short8v o0, o1;
    #pragma unroll
    for (int jj = 0; jj < 8; ++jj) o0[jj] = f2bf(tile[seg * 16 + jj][r]);
    #pragma unroll
    for (int jj = 0; jj < 8; ++jj) o1[jj] = f2bf(tile[seg * 16 + 8 + jj][r]);
    *(short8v*)(o)     = o0;
    *(short8v*)(o + 8) = o1;
}

// ---------------------------------------------------------------------------
// Wp [768][768] fp32 -> wpt [768][768] bf16 transposed: wpt[n][c] = Wp[c][n].
// ---------------------------------------------------------------------------
__global__ __launch_bounds__(256) void wp_transpose(
        const float* __restrict__ Wp, short* __restrict__ wpt)
{
    const int n0 = blockIdx.x * 64;
    const int c0 = blockIdx.y * 64;
    __shared__ float tile[64][65];
    const int tid = threadIdx.x;
    const int r = tid >> 2, seg = tid & 3;

    const float* src = Wp + ((size_t)(c0 + r)) * C_ + n0 + seg * 16;
    #pragma unroll
    for (int u = 0; u < 4; ++u) {
        const float4 v = *(const float4*)(src + u * 4);
        tile[r][seg * 16 + u * 4 + 0] = v.x;
        tile[r][seg * 16 + u * 4 + 1] = v.y;
        tile[r][seg * 16 + u * 4 + 2] = v.z;
        tile[r][seg * 16 + u * 4 + 3] = v.w;
    }
    __syncthreads();
    short* o = wpt + ((size_t)(n0 + r)) * C_ + c0 + seg * 16;
    short8v o0, o1;
    #pragma unroll
    for (int jj = 0; jj < 8; ++jj) o0[jj] = f2bf(tile[seg * 16 + jj][r]);
    #pragma unroll
    for (int jj = 0; jj < 8; ++jj) o1[jj] = f2bf(tile[seg * 16 + 8 + jj][r]);
    *(short8v*)(o)     = o0;
    *(short8v*)(o + 8) = o1;
}

// ---------------------------------------------------------------------------
// MFMA GEMM core: A [M][768] bf16, Bt [N-rows][768] bf16 (B transposed).
// 128x128 tile, BK=64, 256 thr = 4 waves (2x2), 4x4 16x16 frags/wave.
// Staging via global_load_lds width 16 (linear LDS [128][64]).
// ---------------------------------------------------------------------------

__global__ __launch_bounds__(256) void qkv_mfma(
        const short* __restrict__ xb, const short* __restrict__ wt,
        short* __restrict__ qb, short* __restrict__ kb, short* __restrict__ vb)
{
    const int z = blockIdx.z;
    const short* Bt = wt + (size_t)z * C_ * C_;
    short* out = (z == 0) ? qb : ((z == 1) ? kb : vb);
    const float osc = (z == 0) ? 0.125f : 1.0f;

    const int n0 = blockIdx.x * BN;
    const int m0 = blockIdx.y * BM;

    __shared__ short As[BM * BK];
    __shared__ short Bs[BN * BK];

    const int tid = threadIdx.x;
    const int w = tid >> 6, l = tid & 63, lg = l >> 4, lc = l & 15;
    const int wr = w >> 1, wc = w & 1;
    const int tmod8 = (tid & 7) * 8;

    f32x4 acc[4][4];
    #pragma unroll
    for (int i = 0; i < 4; ++i)
        #pragma unroll
        for (int j = 0; j < 4; ++j) acc[i][j] = (f32x4){0.f, 0.f, 0.f, 0.f};

    for (int k0 = 0; k0 < C_; k0 += BK) {
        #pragma unroll
        for (int it = 0; it < 4; ++it) {
            const int t = it * 256 + tid;
            const int row = t >> 3;
            gload16(xb + ((size_t)(m0 + row)) * C_ + k0 + tmod8, As + t * 8);
            gload16(Bt + ((size_t)(n0 + row)) * C_ + k0 + tmod8, Bs + t * 8);
        }
        __syncthreads();
        #pragma unroll
        for (int ks = 0; ks < 2; ++ks) {
            short8v af[4], bfv[4];
            #pragma unroll
            for (int i = 0; i < 4; ++i)
                af[i] = *(const short8v*)(As + (wr * 64 + i * 16 + lc) * BK + ks * 32 + lg * 8);
            #pragma unroll
            for (int j = 0; j < 4; ++j)
                bfv[j] = *(const short8v*)(Bs + (wc * 64 + j * 16 + lc) * BK + ks * 32 + lg * 8);
            #pragma unroll
            for (int i = 0; i < 4; ++i)
                #pragma unroll
                for (int j = 0; j < 4; ++j)
                    acc[i][j] = __builtin_amdgcn_mfma_f32_16x16x32_bf16(af[i], bfv[j], acc[i][j], 0, 0, 0);
        }
        __syncthreads();
    }

    // epilogue: out bf16 [B,H,T,64]; h uniform per wave, d = j*16 + lc
    const int h = blockIdx.x * 2 + wc;
    #pragma unroll
    for (int i = 0; i < 4; ++i) {
        #pragma unroll
        for (int r = 0; r < 4; ++r) {
            const int m  = m0 + wr * 64 + i * 16 + lg * 4 + r;
            const int bb = m >> 10, tt = m & (T_ - 1);
            short* op = out + (((size_t)(bb * H_ + h)) * T_ + tt) * 64;
            #pragma unroll
            for (int j = 0; j < 4; ++j)
                op[j * 16 + lc] = f2bf(acc[i][j][r] * osc);
        }
    }
}

__global__ __launch_bounds__(256) void proj_mfma(
        const short* __restrict__ ab, const short* __restrict__ wpt,
        const float* __restrict__ bp, float* __restrict__ out)
{
    const int n0 = blockIdx.x * BN;
    const int m0 = blockIdx.y * BM;

    __shared__ short As[BM * BK];
    __shared__ short Bs[BN * BK];

    const int tid = threadIdx.x;
    const int w = tid >> 6, l = tid & 63, lg = l >> 4, lc = l & 15;
    const int wr = w >> 1, wc = w & 1;
    const int tmod8 = (tid & 7) * 8;

    f32x4 acc[4][4];
    #pragma unroll
    for (int i = 0; i < 4; ++i)
        #pragma unroll
        for (int j = 0; j < 4; ++j) acc[i][j] = (f32x4){0.f, 0.f, 0.f, 0.f};

    for (int k0 = 0; k0 < C_; k0 += BK) {
        #pragma unroll
        for (int it = 0; it < 4; ++it) {
            const int t = it * 256 + tid;
            const int row = t >> 3;
            gload16(ab  + ((size_t)(m0 + row)) * C_ + k0 + tmod8, As + t * 8);
            gload16(wpt + ((size_t)(n0 + row)) * C_ + k0 + tmod8, Bs + t * 8);
        }
        __syncthreads();
        #pragma unroll
        for (int ks = 0; ks < 2; ++ks) {
            short8v af[4], bfv[4];
            #pragma unroll
            for (int i = 0; i < 4; ++i)
                af[i] = *(const short8v*)(As + (wr * 64 + i * 16 + lc) * BK + ks * 32 + lg * 8);
            #pragma unroll
            for (int j = 0; j < 4; ++j)
                bfv[j] = *(const short8v*)(Bs + (wc * 64 + j * 16 + lc) * BK + ks * 32 + lg * 8);
            #pragma unroll
            for (int i = 0; i < 4; ++i)
                #pragma unroll
                for (int j = 0; j < 4; ++j)
                    acc[i][j] = __builtin_amdgcn_mfma_f32_16x16x32_bf16(af[i], bfv[j], acc[i][j], 0, 0, 0);
        }
        __syncthreads();
    }

    float bias[4];
    #pragma unroll
    for (int j = 0; j < 4; ++j) bias[j] = bp[n0 + wc * 64 + j * 16 + lc];
    #pragma unroll
    for (int i = 0; i < 4; ++i) {
        #pragma unroll
        for (int r = 0; r < 4; ++r) {
            const int m = m0 + wr * 64 + i * 16 + lg * 4 + r;
            float* op = out + (size_t)m * C_ + n0 + wc * 64 + lc;
            #pragma unroll
            for (int j = 0; j < 4; ++j)
                op[j * 16] = acc[i][j][r] + bias[j];
        }
    }
}

// ---------------------------------------------------------------------------
// V transpose per head: [B,H,T,64] -> [B,H,64,T] (bf16), 64x64 tiles.
// ---------------------------------------------------------------------------
__global__ __launch_bounds__(256) void v_transpose(
        const __hip_bfloat16* __restrict__ vb, __hip_bfloat16* __restrict__ vt)
{
    const int t0 = blockIdx.x * 64;
    const int h  = blockIdx.y;
    const int b  = blockIdx.z;
    __shared__ short tile[64][72];
    const int tid = threadIdx.x;
    const int r   = tid >> 2;
    const int seg = tid & 3;

    const short* src = (const short*)vb +
        (((size_t)(b * H_ + h)) * T_ + t0 + r) * 64 + seg * 16;
    *(short8v*)(&tile[r][seg * 16])     = *(const short8v*)(src);
    *(short8v*)(&tile[r][seg * 16 + 8]) = *(const short8v*)(src + 8);
    __syncthreads();

    short* dst = (short*)vt +
        (((size_t)(b * H_ + h)) * 64 + r) * T_ + t0 + seg * 16;
    short8v o0, o1;
    #pragma unroll
    for (int j = 0; j < 8; ++j) o0[j] = tile[seg * 16 + j][r];
    #pragma unroll
    for (int j = 0; j < 8; ++j) o1[j] = tile[seg * 16 + 8 + j][r];
    *(short8v*)(dst)     = o0;
    *(short8v*)(dst + 8) = o1;
}

// ---------------------------------------------------------------------------
// Flash attention, bf16 MFMA (layout verified R4: absmax 0.0078).
// Epilogue now emits bf16 ab [B,T,768] for the MFMA projection.
// ---------------------------------------------------------------------------
__global__ __launch_bounds__(256) void attn_mfma(
        const __hip_bfloat16* __restrict__ qb,
        const __hip_bfloat16* __restrict__ kb,
        const __hip_bfloat16* __restrict__ vt,
        short* __restrict__ ab)
{
    const int bx = blockIdx.x;
    const int h  = blockIdx.y;
    const int b  = blockIdx.z;
    const int tid = threadIdx.x;
    const int w  = tid >> 6;
    const int l  = tid & 63;
    const int lg = l >> 4;
    const int lc = l & 15;

    const int t0 = bx * 64;
    const int q0 = t0 + w * 16;

    const size_t headRow = ((size_t)(b * H_ + h)) * T_;
    const size_t vtRow   = ((size_t)(b * H_ + h)) * 64;

    short8v aq0, aq1;
    {
        const short* qp = (const short*)qb + (headRow + q0 + lc) * 64 + lg * 8;
        aq0 = *(const short8v*)(qp);
        aq1 = *(const short8v*)(qp + 32);
    }

    __shared__ short p_s[4][16][72];

    float m_r[4], l_r[4];
    f32x4 o_acc[4];
    #pragma unroll
    for (int r = 0; r < 4; ++r) { m_r[r] = -1e30f; l_r[r] = 0.0f; }
    #pragma unroll
    for (int n = 0; n < 4; ++n) o_acc[n] = (f32x4){0.f, 0.f, 0.f, 0.f};

    const int ntiles = bx + 1;
    for (int kt = 0; kt < ntiles; ++kt) {
        const int kv0 = kt * 64;

        f32x4 s[4];
        #pragma unroll
        for (int n = 0; n < 4; ++n) {
            const short* kp = (const short*)kb + (headRow + kv0 + n * 16 + lc) * 64 + lg * 8;
            short8v bk0 = *(const short8v*)(kp);
            short8v bk1 = *(const short8v*)(kp + 32);
            f32x4 a2 = (f32x4){0.f, 0.f, 0.f, 0.f};
            a2 = __builtin_amdgcn_mfma_f32_16x16x32_bf16(aq0, bk0, a2, 0, 0, 0);
            a2 = __builtin_amdgcn_mfma_f32_16x16x32_bf16(aq1, bk1, a2, 0, 0, 0);
            s[n] = a2;
        }

        if (kt == ntiles - 1) {
            #pragma unroll
            for (int n = 0; n < 4; ++n) {
                const int kvg = kv0 + n * 16 + lc;
                #pragma unroll
                for (int r = 0; r < 4; ++r) {
                    const int qg = q0 + lg * 4 + r;
                    if (kvg > qg) s[n][r] = -1e30f;
                }
            }
        }

        float p[4][4];
        float pscale[4];
        #pragma unroll
        for (int r = 0; r < 4; ++r) {
            float tm = fmaxf(fmaxf(s[0][r], s[1][r]), fmaxf(s[2][r], s[3][r]));
            #pragma unroll
            for (int mk = 8; mk >= 1; mk >>= 1) tm = fmaxf(tm, __shfl_xor(tm, mk, 16));
            const float mnew = fmaxf(m_r[r], tm);
            pscale[r] = __expf(m_r[r] - mnew);
            float ps = 0.f;
            #pragma unroll
            for (int n = 0; n < 4; ++n) { p[n][r] = __expf(s[n][r] - mnew); ps += p[n][r]; }
            #pragma unroll
            for (int mk = 8; mk >= 1; mk >>= 1) ps += __shfl_xor(ps, mk, 16);
            l_r[r] = l_r[r] * pscale[r] + ps;
            m_r[r] = mnew;
        }
        #pragma unroll
        for (int n = 0; n < 4; ++n)
            #pragma unroll
            for (int r = 0; r < 4; ++r) o_acc[n][r] *= pscale[r];

        #pragma unroll
        for (int n = 0; n < 4; ++n)
            #pragma unroll
            for (int r = 0; r < 4; ++r)
                p_s[w][lg * 4 + r][n * 16 + lc] = f2bf(p[n][r]);
        __syncthreads();

        const short* prow = &p_s[w][lc][lg * 8];
        short8v pa0 = *(const short8v*)(prow);
        short8v pa1 = *(const short8v*)(prow + 32);
        #pragma unroll
        for (int n = 0; n < 4; ++n) {
            const short* vp = (const short*)vt + (vtRow + n * 16 + lc) * T_ + kv0 + lg * 8;
            short8v bv0 = *(const short8v*)(vp);
            short8v bv1 = *(const short8v*)(vp + 32);
            o_acc[n] = __builtin_amdgcn_mfma_f32_16x16x32_bf16(pa0, bv0, o_acc[n], 0, 0, 0);
            o_acc[n] = __builtin_amdgcn_mfma_f32_16x16x32_bf16(pa1, bv1, o_acc[n], 0, 0, 0);
        }
    }

    #pragma unroll
    for (int r = 0; r < 4; ++r) {
        const float inv = 1.0f / l_r[r];
        const int q = q0 + lg * 4 + r;
        short* op = ab + ((size_t)(b * T_) + q) * C_ + h * 64 + lc;
        #pragma unroll
        for (int n = 0; n < 4; ++n) op[n * 16] = f2bf(o_acc[n][r] * inv);
    }
}

// ---------------------------------------------------------------------------

extern "C" void kernel_launch(void* const* d_in, const int* in_sizes, int n_in,
                              void* d_out, int out_size, void* d_ws, size_t ws_size,
                              hipStream_t stream)
{
    const float* x  = (const float*)d_in[0];
    const float* Wq = (const float*)d_in[1];
    const float* Wk = (const float*)d_in[2];
    const float* Wv = (const float*)d_in[3];
    const float* Wp = (const float*)d_in[4];
    const float* bp = (const float*)d_in[5];
    float* out = (float*)d_out;

    char* ws = (char*)d_ws;
    const size_t NE = (size_t)B_ * T_ * C_;          // 6,291,456
    const size_t BF = NE * sizeof(short);            // 12.58 MB
    short* xb  = (short*)(ws);
    short* qb  = (short*)(ws + BF);
    short* kb  = (short*)(ws + 2 * BF);
    short* vb  = (short*)(ws + 3 * BF);
    short* vt  = (short*)(ws + 4 * BF);
    short* ab  = (short*)(ws + 5 * BF);
    short* wt  = (short*)(ws + 6 * BF);                       // 3 x 768 x 768 bf16
    short* wpt = (short*)(ws + 6 * BF + 3 * C_ * C_ * 2);     // 768 x 768 bf16

    // prep: conversions + weight transposes
    x_to_bf16<<<dim3(NE / (256 * 8)), dim3(256), 0, stream>>>(x, xb);
    w_transpose<<<dim3(12, 12, 3), dim3(256), 0, stream>>>(Wq, Wk, Wv, wt);
    wp_transpose<<<dim3(12, 12), dim3(256), 0, stream>>>(Wp, wpt);

    // 1) QKV projections (MFMA) -> bf16 [B,H,T,64]
    qkv_mfma<<<dim3(C_ / BN, (B_ * T_) / BM, 3), dim3(256), 0, stream>>>(
        xb, wt, qb, kb, vb);

    // 2) V transpose -> [B,H,64,T]
    v_transpose<<<dim3(T_ / 64, H_, B_), dim3(256), 0, stream>>>(
        (const __hip_bfloat16*)vb, (__hip_bfloat16*)vt);

    // 3) causal flash attention (MFMA) -> ab bf16 [B,T,C]
    attn_mfma<<<dim3(T_ / 64, H_, B_), dim3(256), 0, stream>>>(
        (const __hip_bfloat16*)qb, (const __hip_bfloat16*)kb,
        (const __hip_bfloat16*)vt, ab);

    // 4) output projection (MFMA) + bias -> d_out fp32
    proj_mfma<<<dim3(C_ / BN, (B_ * T_) / BM), dim3(256), 0, stream>>>(
        ab, wpt, bp, out);
}

// Round 11
// 276.677 us; speedup vs baseline: 6.5029x; 1.3274x over previous
//
#include <hip/hip_runtime.h>
#include <hip/hip_bf16.h>
#include <cstdint>

#define B_  8
#define T_  1024
#define C_  768
#define H_  12
#define DH_ 64

#define BM 128
#define BN 128
#define BK 64

typedef __attribute__((ext_vector_type(8))) short short8v;
typedef __attribute__((ext_vector_type(4))) short short4v;
typedef __attribute__((ext_vector_type(4))) float f32x4;

static __device__ __forceinline__ short f2bf(float x) {
    __hip_bfloat16 h = __float2bfloat16(x);
    return *reinterpret_cast<const short*>(&h);
}

static __device__ __forceinline__ void gload16(const short* g, short* l) {
    __builtin_amdgcn_global_load_lds(
        (const __attribute__((address_space(1))) unsigned int*)g,
        (__attribute__((address_space(3))) unsigned int*)l, 16, 0, 0);
}

// ---------------------------------------------------------------------------
// x fp32 [8192][768] -> bf16 (same layout). 8 elems/thread.
// ---------------------------------------------------------------------------
__global__ __launch_bounds__(256) void x_to_bf16(
        const float* __restrict__ x, short* __restrict__ xb)
{
    const size_t i = ((size_t)blockIdx.x * 256 + threadIdx.x) * 8;
    const float4 a = *(const float4*)(x + i);
    const float4 b = *(const float4*)(x + i + 4);
    short8v o;
    o[0] = f2bf(a.x); o[1] = f2bf(a.y); o[2] = f2bf(a.z); o[3] = f2bf(a.w);
    o[4] = f2bf(b.x); o[5] = f2bf(b.y); o[6] = f2bf(b.z); o[7] = f2bf(b.w);
    *(short8v*)(xb + i) = o;
}

// ---------------------------------------------------------------------------
// Wq/Wk/Wv [H][768][64] fp32 -> wt [3][768][768] bf16, transposed per head:
// wt[z][h*64+d][c] = W[z][h][c][d].  Tiles 64x64, grid (12, 12, 3).
// ---------------------------------------------------------------------------
__global__ __launch_bounds__(256) void w_transpose(
        const float* __restrict__ Wq, const float* __restrict__ Wk,
        const float* __restrict__ Wv, short* __restrict__ wt)
{
    const int z = blockIdx.z;
    const float* W = (z == 0) ? Wq : ((z == 1) ? Wk : Wv);
    short* dst = wt + (size_t)z * C_ * C_;
    const int c0 = blockIdx.x * 64;
    const int h  = blockIdx.y;
    __shared__ float tile[64][65];
    const int tid = threadIdx.x;
    const int r = tid >> 2, seg = tid & 3;

    const float* src = W + ((size_t)h * C_ + c0 + r) * 64 + seg * 16;
    #pragma unroll
    for (int u = 0; u < 4; ++u) {
        const float4 v = *(const float4*)(src + u * 4);
        tile[r][seg * 16 + u * 4 + 0] = v.x;
        tile[r][seg * 16 + u * 4 + 1] = v.y;
        tile[r][seg * 16 + u * 4 + 2] = v.z;
        tile[r][seg * 16 + u * 4 + 3] = v.w;
    }
    __syncthreads();
    short* o = dst + ((size_t)h * 64 + r) * C_ + c0 + seg * 16;
    short8v o0, o1;
    #pragma unroll
    for (int jj = 0; jj < 8; ++jj) o0[jj] = f2bf(tile[seg * 16 + jj][r]);
    #pragma unroll
    for (int jj = 0; jj < 8; ++jj) o1[jj] = f2bf(tile[seg * 16 + 8 + jj][r]);
    *(short8v*)(o)     = o0;
    *(short8v*)(o + 8) = o1;
}

// ---------------------------------------------------------------------------
// Wp [768][768] fp32 -> wpt [768][768] bf16 transposed: wpt[n][c] = Wp[c][n].
// ---------------------------------------------------------------------------
__global__ __launch_bounds__(256) void wp_transpose(
        const float* __restrict__ Wp, short* __restrict__ wpt)
{
    const int n0 = blockIdx.x * 64;
    const int c0 = blockIdx.y * 64;
    __shared__ float tile[64][65];
    const int tid = threadIdx.x;
    const int r = tid >> 2, seg = tid & 3;

    const float* src = Wp + ((size_t)(c0 + r)) * C_ + n0 + seg * 16;
    #pragma unroll
    for (int u = 0; u < 4; ++u) {
        const float4 v = *(const float4*)(src + u * 4);
        tile[r][seg * 16 + u * 4 + 0] = v.x;
        tile[r][seg * 16 + u * 4 + 1] = v.y;
        tile[r][seg * 16 + u * 4 + 2] = v.z;
        tile[r][seg * 16 + u * 4 + 3] = v.w;
    }
    __syncthreads();
    short* o = wpt + ((size_t)(n0 + r)) * C_ + c0 + seg * 16;
    short8v o0, o1;
    #pragma unroll
    for (int jj = 0; jj < 8; ++jj) o0[jj] = f2bf(tile[seg * 16 + jj][r]);
    #pragma unroll
    for (int jj = 0; jj < 8; ++jj) o1[jj] = f2bf(tile[seg * 16 + 8 + jj][r]);
    *(short8v*)(o)     = o0;
    *(short8v*)(o + 8) = o1;
}

// ---------------------------------------------------------------------------
// MFMA GEMM core: A [M][768] bf16, Bt [N-rows][768] bf16 (B transposed).
// 128x128 tile, BK=64, 256 thr = 4 waves (2x2), 4x4 16x16 frags/wave.
// Staging via global_load_lds width 16 (linear LDS [128][64]).
// ---------------------------------------------------------------------------

__global__ __launch_bounds__(256) void qkv_mfma(
        const short* __restrict__ xb, const short* __restrict__ wt,
        short* __restrict__ qb, short* __restrict__ kb, short* __restrict__ vb)
{
    const int z = blockIdx.z;
    const short* Bt = wt + (size_t)z * C_ * C_;
    short* out = (z == 0) ? qb : ((z == 1) ? kb : vb);
    const float osc = (z == 0) ? 0.125f : 1.0f;

    const int n0 = blockIdx.x * BN;
    const int m0 = blockIdx.y * BM;

    __shared__ short As[BM * BK];
    __shared__ short Bs[BN * BK];

    const int tid = threadIdx.x;
    const int w = tid >> 6, l = tid & 63, lg = l >> 4, lc = l & 15;
    const int wr = w >> 1, wc = w & 1;
    const int tmod8 = (tid & 7) * 8;

    f32x4 acc[4][4];
    #pragma unroll
    for (int i = 0; i < 4; ++i)
        #pragma unroll
        for (int j = 0; j < 4; ++j) acc[i][j] = (f32x4){0.f, 0.f, 0.f, 0.f};

    for (int k0 = 0; k0 < C_; k0 += BK) {
        #pragma unroll
        for (int it = 0; it < 4; ++it) {
            const int t = it * 256 + tid;
            const int row = t >> 3;
            gload16(xb + ((size_t)(m0 + row)) * C_ + k0 + tmod8, As + t * 8);
            gload16(Bt + ((size_t)(n0 + row)) * C_ + k0 + tmod8, Bs + t * 8);
        }
        __syncthreads();
        #pragma unroll
        for (int ks = 0; ks < 2; ++ks) {
            short8v af[4], bfv[4];
            #pragma unroll
            for (int i = 0; i < 4; ++i)
                af[i] = *(const short8v*)(As + (wr * 64 + i * 16 + lc) * BK + ks * 32 + lg * 8);
            #pragma unroll
            for (int j = 0; j < 4; ++j)
                bfv[j] = *(const short8v*)(Bs + (wc * 64 + j * 16 + lc) * BK + ks * 32 + lg * 8);
            #pragma unroll
            for (int i = 0; i < 4; ++i)
                #pragma unroll
                for (int j = 0; j < 4; ++j)
                    acc[i][j] = __builtin_amdgcn_mfma_f32_16x16x32_bf16(af[i], bfv[j], acc[i][j], 0, 0, 0);
        }
        __syncthreads();
    }

    // epilogue: out bf16 [B,H,T,64]; h uniform per wave, d = j*16 + lc
    const int h = blockIdx.x * 2 + wc;
    #pragma unroll
    for (int i = 0; i < 4; ++i) {
        #pragma unroll
        for (int r = 0; r < 4; ++r) {
            const int m  = m0 + wr * 64 + i * 16 + lg * 4 + r;
            const int bb = m >> 10, tt = m & (T_ - 1);
            short* op = out + (((size_t)(bb * H_ + h)) * T_ + tt) * 64;
            #pragma unroll
            for (int j = 0; j < 4; ++j)
                op[j * 16 + lc] = f2bf(acc[i][j][r] * osc);
        }
    }
}

__global__ __launch_bounds__(256) void proj_mfma(
        const short* __restrict__ ab, const short* __restrict__ wpt,
        const float* __restrict__ bp, float* __restrict__ out)
{
    const int n0 = blockIdx.x * BN;
    const int m0 = blockIdx.y * BM;

    __shared__ short As[BM * BK];
    __shared__ short Bs[BN * BK];

    const int tid = threadIdx.x;
    const int w = tid >> 6, l = tid & 63, lg = l >> 4, lc = l & 15;
    const int wr = w >> 1, wc = w & 1;
    const int tmod8 = (tid & 7) * 8;

    f32x4 acc[4][4];
    #pragma unroll
    for (int i = 0; i < 4; ++i)
        #pragma unroll
        for (int j = 0; j < 4; ++j) acc[i][j] = (f32x4){0.f, 0.f, 0.f, 0.f};

    for (int k0 = 0; k0 < C_; k0 += BK) {
        #pragma unroll
        for (int it = 0; it < 4; ++it) {
            const int t = it * 256 + tid;
            const int row = t >> 3;
            gload16(ab  + ((size_t)(m0 + row)) * C_ + k0 + tmod8, As + t * 8);
            gload16(wpt + ((size_t)(n0 + row)) * C_ + k0 + tmod8, Bs + t * 8);
        }
        __syncthreads();
        #pragma unroll
        for (int ks = 0; ks < 2; ++ks) {
            short8v af[4], bfv[4];
            #pragma unroll
            for (int i = 0; i < 4; ++i)
                af[i] = *(const short8v*)(As + (wr * 64 + i * 16 + lc) * BK + ks * 32 + lg * 8);
            #pragma unroll
            for (int j = 0; j < 4; ++j)
                bfv[j] = *(const short8v*)(Bs + (wc * 64 + j * 16 + lc) * BK + ks * 32 + lg * 8);
            #pragma unroll
            for (int i = 0; i < 4; ++i)
                #pragma unroll
                for (int j = 0; j < 4; ++j)
                    acc[i][j] = __builtin_amdgcn_mfma_f32_16x16x32_bf16(af[i], bfv[j], acc[i][j], 0, 0, 0);
        }
        __syncthreads();
    }

    float bias[4];
    #pragma unroll
    for (int j = 0; j < 4; ++j) bias[j] = bp[n0 + wc * 64 + j * 16 + lc];
    #pragma unroll
    for (int i = 0; i < 4; ++i) {
        #pragma unroll
        for (int r = 0; r < 4; ++r) {
            const int m = m0 + wr * 64 + i * 16 + lg * 4 + r;
            float* op = out + (size_t)m * C_ + n0 + wc * 64 + lc;
            #pragma unroll
            for (int j = 0; j < 4; ++j)
                op[j * 16] = acc[i][j][r] + bias[j];
        }
    }
}

// ---------------------------------------------------------------------------
// V transpose per head: [B,H,T,64] -> [B,H,64,T] (bf16), 64x64 tiles.
// ---------------------------------------------------------------------------
__global__ __launch_bounds__(256) void v_transpose(
        const __hip_bfloat16* __restrict__ vb, __hip_bfloat16* __restrict__ vt)
{
    const int t0 = blockIdx.x * 64;
    const int h  = blockIdx.y;
    const int b  = blockIdx.z;
    __shared__ short tile[64][72];
    const int tid = threadIdx.x;
    const int r   = tid >> 2;
    const int seg = tid & 3;

    const short* src = (const short*)vb +
        (((size_t)(b * H_ + h)) * T_ + t0 + r) * 64 + seg * 16;
    *(short8v*)(&tile[r][seg * 16])     = *(const short8v*)(src);
    *(short8v*)(&tile[r][seg * 16 + 8]) = *(const short8v*)(src + 8);
    __syncthreads();

    short* dst = (short*)vt +
        (((size_t)(b * H_ + h)) * 64 + r) * T_ + t0 + seg * 16;
    short8v o0, o1;
    #pragma unroll
    for (int j = 0; j < 8; ++j) o0[j] = tile[seg * 16 + j][r];
    #pragma unroll
    for (int j = 0; j < 8; ++j) o1[j] = tile[seg * 16 + 8 + j][r];
    *(short8v*)(dst)     = o0;
    *(short8v*)(dst + 8) = o1;
}

// ---------------------------------------------------------------------------
// Flash attention, bf16 MFMA. Grid (8, H, B); block bx handles q-tiles
// {bx, 15-bx} sequentially -> every block runs exactly 17 KV-tile iters
// (causal load balance). 4 waves, wave w owns rows [q0+16w, q0+16w+16).
// V fragments prefetched before softmax; no block barrier (P tile is
// per-wave private; intra-wave lgkmcnt ordering is compiler-enforced).
// ---------------------------------------------------------------------------
__global__ __launch_bounds__(256) void attn_mfma(
        const __hip_bfloat16* __restrict__ qb,
        const __hip_bfloat16* __restrict__ kb,
        const __hip_bfloat16* __restrict__ vt,
        short* __restrict__ ab)
{
    const int bx = blockIdx.x;          // 0..7
    const int h  = blockIdx.y;
    const int b  = blockIdx.z;
    const int tid = threadIdx.x;
    const int w  = tid >> 6;
    const int l  = tid & 63;
    const int lg = l >> 4;
    const int lc = l & 15;

    const size_t headRow = ((size_t)(b * H_ + h)) * T_;
    const size_t vtRow   = ((size_t)(b * H_ + h)) * 64;

    __shared__ short p_s[4][16][72];

    #pragma unroll
    for (int phase = 0; phase < 2; ++phase) {
        const int qt = (phase == 0) ? bx : (15 - bx);
        const int q0 = qt * 64 + w * 16;

        short8v aq0, aq1;
        {
            const short* qp = (const short*)qb + (headRow + q0 + lc) * 64 + lg * 8;
            aq0 = *(const short8v*)(qp);
            aq1 = *(const short8v*)(qp + 32);
        }

        float m_r[4], l_r[4];
        f32x4 o_acc[4];
        #pragma unroll
        for (int r = 0; r < 4; ++r) { m_r[r] = -1e30f; l_r[r] = 0.0f; }
        #pragma unroll
        for (int n = 0; n < 4; ++n) o_acc[n] = (f32x4){0.f, 0.f, 0.f, 0.f};

        for (int kt = 0; kt <= qt; ++kt) {
            const int kv0 = kt * 64;

            // K fragments + V prefetch (V latency hides under QK^T+softmax)
            short8v bk0[4], bk1[4], bv0[4], bv1[4];
            #pragma unroll
            for (int n = 0; n < 4; ++n) {
                const short* kp = (const short*)kb + (headRow + kv0 + n * 16 + lc) * 64 + lg * 8;
                bk0[n] = *(const short8v*)(kp);
                bk1[n] = *(const short8v*)(kp + 32);
                const short* vp = (const short*)vt + (vtRow + n * 16 + lc) * T_ + kv0 + lg * 8;
                bv0[n] = *(const short8v*)(vp);
                bv1[n] = *(const short8v*)(vp + 32);
            }

            f32x4 s[4];
            #pragma unroll
            for (int n = 0; n < 4; ++n) {
                f32x4 a2 = (f32x4){0.f, 0.f, 0.f, 0.f};
                a2 = __builtin_amdgcn_mfma_f32_16x16x32_bf16(aq0, bk0[n], a2, 0, 0, 0);
                a2 = __builtin_amdgcn_mfma_f32_16x16x32_bf16(aq1, bk1[n], a2, 0, 0, 0);
                s[n] = a2;
            }

            if (kt == qt) {   // diagonal tile: causal mask
                #pragma unroll
                for (int n = 0; n < 4; ++n) {
                    const int kvg = kv0 + n * 16 + lc;
                    #pragma unroll
                    for (int r = 0; r < 4; ++r) {
                        const int qg = q0 + lg * 4 + r;
                        if (kvg > qg) s[n][r] = -1e30f;
                    }
                }
            }

            float p[4][4];
            float pscale[4];
            #pragma unroll
            for (int r = 0; r < 4; ++r) {
                float tm = fmaxf(fmaxf(s[0][r], s[1][r]), fmaxf(s[2][r], s[3][r]));
                #pragma unroll
                for (int mk = 8; mk >= 1; mk >>= 1) tm = fmaxf(tm, __shfl_xor(tm, mk, 16));
                const float mnew = fmaxf(m_r[r], tm);
                pscale[r] = __expf(m_r[r] - mnew);
                float ps = 0.f;
                #pragma unroll
                for (int n = 0; n < 4; ++n) { p[n][r] = __expf(s[n][r] - mnew); ps += p[n][r]; }
                #pragma unroll
                for (int mk = 8; mk >= 1; mk >>= 1) ps += __shfl_xor(ps, mk, 16);
                l_r[r] = l_r[r] * pscale[r] + ps;
                m_r[r] = mnew;
            }
            #pragma unroll
            for (int n = 0; n < 4; ++n)
                #pragma unroll
                for (int r = 0; r < 4; ++r) o_acc[n][r] *= pscale[r];

            // P -> per-wave LDS tile (no block barrier needed)
            #pragma unroll
            for (int n = 0; n < 4; ++n)
                #pragma unroll
                for (int r = 0; r < 4; ++r)
                    p_s[w][lg * 4 + r][n * 16 + lc] = f2bf(p[n][r]);

            const short* prow = &p_s[w][lc][lg * 8];
            short8v pa0 = *(const short8v*)(prow);
            short8v pa1 = *(const short8v*)(prow + 32);
            #pragma unroll
            for (int n = 0; n < 4; ++n) {
                o_acc[n] = __builtin_amdgcn_mfma_f32_16x16x32_bf16(pa0, bv0[n], o_acc[n], 0, 0, 0);
                o_acc[n] = __builtin_amdgcn_mfma_f32_16x16x32_bf16(pa1, bv1[n], o_acc[n], 0, 0, 0);
            }
        }

        #pragma unroll
        for (int r = 0; r < 4; ++r) {
            const float inv = 1.0f / l_r[r];
            const int q = q0 + lg * 4 + r;
            short* op = ab + ((size_t)(b * T_) + q) * C_ + h * 64 + lc;
            #pragma unroll
            for (int n = 0; n < 4; ++n) op[n * 16] = f2bf(o_acc[n][r] * inv);
        }
    }
}

// ---------------------------------------------------------------------------

extern "C" void kernel_launch(void* const* d_in, const int* in_sizes, int n_in,
                              void* d_out, int out_size, void* d_ws, size_t ws_size,
                              hipStream_t stream)
{
    const float* x  = (const float*)d_in[0];
    const float* Wq = (const float*)d_in[1];
    const float* Wk = (const float*)d_in[2];
    const float* Wv = (const float*)d_in[3];
    const float* Wp = (const float*)d_in[4];
    const float* bp = (const float*)d_in[5];
    float* out = (float*)d_out;

    char* ws = (char*)d_ws;
    const size_t NE = (size_t)B_ * T_ * C_;          // 6,291,456
    const size_t BF = NE * sizeof(short);            // 12.58 MB
    short* xb  = (short*)(ws);
    short* qb  = (short*)(ws + BF);
    short* kb  = (short*)(ws + 2 * BF);
    short* vb  = (short*)(ws + 3 * BF);
    short* vt  = (short*)(ws + 4 * BF);
    short* ab  = (short*)(ws + 5 * BF);
    short* wt  = (short*)(ws + 6 * BF);                       // 3 x 768 x 768 bf16
    short* wpt = (short*)(ws + 6 * BF + 3 * C_ * C_ * 2);     // 768 x 768 bf16

    // prep: conversions + weight transposes
    x_to_bf16<<<dim3(NE / (256 * 8)), dim3(256), 0, stream>>>(x, xb);
    w_transpose<<<dim3(12, 12, 3), dim3(256), 0, stream>>>(Wq, Wk, Wv, wt);
    wp_transpose<<<dim3(12, 12), dim3(256), 0, stream>>>(Wp, wpt);

    // 1) QKV projections (MFMA) -> bf16 [B,H,T,64]
    qkv_mfma<<<dim3(C_ / BN, (B_ * T_) / BM, 3), dim3(256), 0, stream>>>(
        xb, wt, qb, kb, vb);

    // 2) V transpose -> [B,H,64,T]
    v_transpose<<<dim3(T_ / 64, H_, B_), dim3(256), 0, stream>>>(
        (const __hip_bfloat16*)vb, (__hip_bfloat16*)vt);

    // 3) causal flash attention (MFMA, tile-paired balanced) -> ab bf16 [B,T,C]
    attn_mfma<<<dim3(8, H_, B_), dim3(256), 0, stream>>>(
        (const __hip_bfloat16*)qb, (const __hip_bfloat16*)kb,
        (const __hip_bfloat16*)vt, ab);

    // 4) output projection (MFMA) + bias -> d_out fp32
    proj_mfma<<<dim3(C_ / BN, (B_ * T_) / BM), dim3(256), 0, stream>>>(
        ab, wpt, bp, out);
}

// Round 13
// 241.717 us; speedup vs baseline: 7.4434x; 1.1446x over previous
//
#include <hip/hip_runtime.h>
#include <hip/hip_bf16.h>
#include <cstdint>

#define B_  8
#define T_  1024
#define C_  768
#define H_  12
#define DH_ 64

#define BM 128
#define BN 128
#define BK 64

typedef __attribute__((ext_vector_type(8))) short short8v;
typedef __attribute__((ext_vector_type(4))) short short4v;
typedef __attribute__((ext_vector_type(4))) float f32x4;

static __device__ __forceinline__ short f2bf(float x) {
    __hip_bfloat16 h = __float2bfloat16(x);
    return *reinterpret_cast<const short*>(&h);
}

static __device__ __forceinline__ void gload16(const short* g, short* l) {
    __builtin_amdgcn_global_load_lds(
        (const __attribute__((address_space(1))) unsigned int*)g,
        (__attribute__((address_space(3))) unsigned int*)l, 16, 0, 0);
}

// ---------------------------------------------------------------------------
// x fp32 [8192][768] -> bf16 (same layout). 8 elems/thread.
// ---------------------------------------------------------------------------
__global__ __launch_bounds__(256) void x_to_bf16(
        const float* __restrict__ x, short* __restrict__ xb)
{
    const size_t i = ((size_t)blockIdx.x * 256 + threadIdx.x) * 8;
    const float4 a = *(const float4*)(x + i);
    const float4 b = *(const float4*)(x + i + 4);
    short8v o;
    o[0] = f2bf(a.x); o[1] = f2bf(a.y); o[2] = f2bf(a.z); o[3] = f2bf(a.w);
    o[4] = f2bf(b.x); o[5] = f2bf(b.y); o[6] = f2bf(b.z); o[7] = f2bf(b.w);
    *(short8v*)(xb + i) = o;
}

// ---------------------------------------------------------------------------
// Wq/Wk/Wv [H][768][64] fp32 -> wt [3][768][768] bf16, transposed per head:
// wt[z][h*64+d][c] = W[z][h][c][d].  Tiles 64x64, grid (12, 12, 3).
// ---------------------------------------------------------------------------
__global__ __launch_bounds__(256) void w_transpose(
        const float* __restrict__ Wq, const float* __restrict__ Wk,
        const float* __restrict__ Wv, short* __restrict__ wt)
{
    const int z = blockIdx.z;
    const float* W = (z == 0) ? Wq : ((z == 1) ? Wk : Wv);
    short* dst = wt + (size_t)z * C_ * C_;
    const int c0 = blockIdx.x * 64;
    const int h  = blockIdx.y;
    __shared__ float tile[64][65];
    const int tid = threadIdx.x;
    const int r = tid >> 2, seg = tid & 3;

    const float* src = W + ((size_t)h * C_ + c0 + r) * 64 + seg * 16;
    #pragma unroll
    for (int u = 0; u < 4; ++u) {
        const float4 v = *(const float4*)(src + u * 4);
        tile[r][seg * 16 + u * 4 + 0] = v.x;
        tile[r][seg * 16 + u * 4 + 1] = v.y;
        tile[r][seg * 16 + u * 4 + 2] = v.z;
        tile[r][seg * 16 + u * 4 + 3] = v.w;
    }
    __syncthreads();
    short* o = dst + ((size_t)h * 64 + r) * C_ + c0 + seg * 16;
    short8v o0, o1;
    #pragma unroll
    for (int jj = 0; jj < 8; ++jj) o0[jj] = f2bf(tile[seg * 16 + jj][r]);
    #pragma unroll
    for (int jj = 0; jj < 8; ++jj) o1[jj] = f2bf(tile[seg * 16 + 8 + jj][r]);
    *(short8v*)(o)     = o0;
    *(short8v*)(o + 8) = o1;
}

// ---------------------------------------------------------------------------
// Wp [768][768] fp32 -> wpt [768][768] bf16 transposed: wpt[n][c] = Wp[c][n].
// ---------------------------------------------------------------------------
__global__ __launch_bounds__(256) void wp_transpose(
        const float* __restrict__ Wp, short* __restrict__ wpt)
{
    const int n0 = blockIdx.x * 64;
    const int c0 = blockIdx.y * 64;
    __shared__ float tile[64][65];
    const int tid = threadIdx.x;
    const int r = tid >> 2, seg = tid & 3;

    const float* src = Wp + ((size_t)(c0 + r)) * C_ + n0 + seg * 16;
    #pragma unroll
    for (int u = 0; u < 4; ++u) {
        const float4 v = *(const float4*)(src + u * 4);
        tile[r][seg * 16 + u * 4 + 0] = v.x;
        tile[r][seg * 16 + u * 4 + 1] = v.y;
        tile[r][seg * 16 + u * 4 + 2] = v.z;
        tile[r][seg * 16 + u * 4 + 3] = v.w;
    }
    __syncthreads();
    short* o = wpt + ((size_t)(n0 + r)) * C_ + c0 + seg * 16;
    short8v o0, o1;
    #pragma unroll
    for (int jj = 0; jj < 8; ++jj) o0[jj] = f2bf(tile[seg * 16 + jj][r]);
    #pragma unroll
    for (int jj = 0; jj < 8; ++jj) o1[jj] = f2bf(tile[seg * 16 + 8 + jj][r]);
    *(short8v*)(o)     = o0;
    *(short8v*)(o + 8) = o1;
}

// ---------------------------------------------------------------------------
// MFMA GEMM core: A [M][768] bf16, Bt [N-rows][768] bf16 (B transposed).
// 128x128 tile, BK=64, 256 thr = 4 waves (2x2), 4x4 16x16 frags/wave.
// Staging via global_load_lds width 16 (linear LDS [128][64]).
// ---------------------------------------------------------------------------

__global__ __launch_bounds__(256) void qkv_mfma(
        const short* __restrict__ xb, const short* __restrict__ wt,
        short* __restrict__ qb, short* __restrict__ kb, short* __restrict__ vb)
{
    const int z = blockIdx.z;
    const short* Bt = wt + (size_t)z * C_ * C_;
    short* out = (z == 0) ? qb : ((z == 1) ? kb : vb);
    const float osc = (z == 0) ? 0.125f : 1.0f;

    const int n0 = blockIdx.x * BN;
    const int m0 = blockIdx.y * BM;

    __shared__ short As[BM * BK];
    __shared__ short Bs[BN * BK];

    const int tid = threadIdx.x;
    const int w = tid >> 6, l = tid & 63, lg = l >> 4, lc = l & 15;
    const int wr = w >> 1, wc = w & 1;
    const int tmod8 = (tid & 7) * 8;

    f32x4 acc[4][4];
    #pragma unroll
    for (int i = 0; i < 4; ++i)
        #pragma unroll
        for (int j = 0; j < 4; ++j) acc[i][j] = (f32x4){0.f, 0.f, 0.f, 0.f};

    for (int k0 = 0; k0 < C_; k0 += BK) {
        #pragma unroll
        for (int it = 0; it < 4; ++it) {
            const int t = it * 256 + tid;
            const int row = t >> 3;
            gload16(xb + ((size_t)(m0 + row)) * C_ + k0 + tmod8, As + t * 8);
            gload16(Bt + ((size_t)(n0 + row)) * C_ + k0 + tmod8, Bs + t * 8);
        }
        __syncthreads();
        #pragma unroll
        for (int ks = 0; ks < 2; ++ks) {
            short8v af[4], bfv[4];
            #pragma unroll
            for (int i = 0; i < 4; ++i)
                af[i] = *(const short8v*)(As + (wr * 64 + i * 16 + lc) * BK + ks * 32 + lg * 8);
            #pragma unroll
            for (int j = 0; j < 4; ++j)
                bfv[j] = *(const short8v*)(Bs + (wc * 64 + j * 16 + lc) * BK + ks * 32 + lg * 8);
            #pragma unroll
            for (int i = 0; i < 4; ++i)
                #pragma unroll
                for (int j = 0; j < 4; ++j)
                    acc[i][j] = __builtin_amdgcn_mfma_f32_16x16x32_bf16(af[i], bfv[j], acc[i][j], 0, 0, 0);
        }
        __syncthreads();
    }

    // epilogue: out bf16 [B,H,T,64]; h uniform per wave, d = j*16 + lc
    const int h = blockIdx.x * 2 + wc;
    #pragma unroll
    for (int i = 0; i < 4; ++i) {
        #pragma unroll
        for (int r = 0; r < 4; ++r) {
            const int m  = m0 + wr * 64 + i * 16 + lg * 4 + r;
            const int bb = m >> 10, tt = m & (T_ - 1);
            short* op = out + (((size_t)(bb * H_ + h)) * T_ + tt) * 64;
            #pragma unroll
            for (int j = 0; j < 4; ++j)
                op[j * 16 + lc] = f2bf(acc[i][j][r] * osc);
        }
    }
}

__global__ __launch_bounds__(256) void proj_mfma(
        const short* __restrict__ ab, const short* __restrict__ wpt,
        const float* __restrict__ bp, float* __restrict__ out)
{
    const int n0 = blockIdx.x * BN;
    const int m0 = blockIdx.y * BM;

    __shared__ short As[BM * BK];
    __shared__ short Bs[BN * BK];

    const int tid = threadIdx.x;
    const int w = tid >> 6, l = tid & 63, lg = l >> 4, lc = l & 15;
    const int wr = w >> 1, wc = w & 1;
    const int tmod8 = (tid & 7) * 8;

    f32x4 acc[4][4];
    #pragma unroll
    for (int i = 0; i < 4; ++i)
        #pragma unroll
        for (int j = 0; j < 4; ++j) acc[i][j] = (f32x4){0.f, 0.f, 0.f, 0.f};

    for (int k0 = 0; k0 < C_; k0 += BK) {
        #pragma unroll
        for (int it = 0; it < 4; ++it) {
            const int t = it * 256 + tid;
            const int row = t >> 3;
            gload16(ab  + ((size_t)(m0 + row)) * C_ + k0 + tmod8, As + t * 8);
            gload16(wpt + ((size_t)(n0 + row)) * C_ + k0 + tmod8, Bs + t * 8);
        }
        __syncthreads();
        #pragma unroll
        for (int ks = 0; ks < 2; ++ks) {
            short8v af[4], bfv[4];
            #pragma unroll
            for (int i = 0; i < 4; ++i)
                af[i] = *(const short8v*)(As + (wr * 64 + i * 16 + lc) * BK + ks * 32 + lg * 8);
            #pragma unroll
            for (int j = 0; j < 4; ++j)
                bfv[j] = *(const short8v*)(Bs + (wc * 64 + j * 16 + lc) * BK + ks * 32 + lg * 8);
            #pragma unroll
            for (int i = 0; i < 4; ++i)
                #pragma unroll
                for (int j = 0; j < 4; ++j)
                    acc[i][j] = __builtin_amdgcn_mfma_f32_16x16x32_bf16(af[i], bfv[j], acc[i][j], 0, 0, 0);
        }
        __syncthreads();
    }

    float bias[4];
    #pragma unroll
    for (int j = 0; j < 4; ++j) bias[j] = bp[n0 + wc * 64 + j * 16 + lc];
    #pragma unroll
    for (int i = 0; i < 4; ++i) {
        #pragma unroll
        for (int r = 0; r < 4; ++r) {
            const int m = m0 + wr * 64 + i * 16 + lg * 4 + r;
            float* op = out + (size_t)m * C_ + n0 + wc * 64 + lc;
            #pragma unroll
            for (int j = 0; j < 4; ++j)
                op[j * 16] = acc[i][j][r] + bias[j];
        }
    }
}

// ---------------------------------------------------------------------------
// V transpose per head: [B,H,T,64] -> [B,H,64,T] (bf16), 64x64 tiles.
// ---------------------------------------------------------------------------
__global__ __launch_bounds__(256) void v_transpose(
        const __hip_bfloat16* __restrict__ vb, __hip_bfloat16* __restrict__ vt)
{
    const int t0 = blockIdx.x * 64;
    const int h  = blockIdx.y;
    const int b  = blockIdx.z;
    __shared__ short tile[64][72];
    const int tid = threadIdx.x;
    const int r   = tid >> 2;
    const int seg = tid & 3;

    const short* src = (const short*)vb +
        (((size_t)(b * H_ + h)) * T_ + t0 + r) * 64 + seg * 16;
    *(short8v*)(&tile[r][seg * 16])     = *(const short8v*)(src);
    *(short8v*)(&tile[r][seg * 16 + 8]) = *(const short8v*)(src + 8);
    __syncthreads();

    short* dst = (short*)vt +
        (((size_t)(b * H_ + h)) * 64 + r) * T_ + t0 + seg * 16;
    short8v o0, o1;
    #pragma unroll
    for (int j = 0; j < 8; ++j) o0[j] = tile[seg * 16 + j][r];
    #pragma unroll
    for (int j = 0; j < 8; ++j) o1[j] = tile[seg * 16 + 8 + j][r];
    *(short8v*)(dst)     = o0;
    *(short8v*)(dst + 8) = o1;
}

// ---------------------------------------------------------------------------
// Flash attention, bf16 MFMA, LDS-staged K/V (double-buffered).
// 1D grid 768 with XCD swizzle: hw block i -> wg=(i%96)*8+i/96, so all 8
// q-tile blocks of one head land on one XCD (12 heads x 256KB = 3MB per L2).
// Block handles q-tiles {bx, 15-bx} = 17 KV iters. Per iter: issue
// global_load_lds for tile kt+1, compute tile kt from LDS, one barrier.
// K/V tiles are loaded ONCE per block (was 4x, once per wave).
// LDS rows are 64 bf16 = 128B = bank period -> frag ds_read_b128 is 2-way
// aliased (free, m136); no swizzle needed.
// ---------------------------------------------------------------------------
__global__ __launch_bounds__(256) void attn_mfma(
        const __hip_bfloat16* __restrict__ qb,
        const __hip_bfloat16* __restrict__ kb,
        const __hip_bfloat16* __restrict__ vt,
        short* __restrict__ ab)
{
    const int ii = blockIdx.x;                  // 0..767
    const int wg = (ii % 96) * 8 + (ii / 96);   // XCD-swizzle decode (bijective)
    const int bx = wg & 7;                      // 0..7
    const int h  = (wg >> 3) % H_;
    const int b  = wg / (8 * H_);
    const int tid = threadIdx.x;
    const int w  = tid >> 6;
    const int l  = tid & 63;
    const int lg = l >> 4;
    const int lc = l & 15;

    const size_t headRow = ((size_t)(b * H_ + h)) * T_;
    const size_t vtRow   = ((size_t)(b * H_ + h)) * 64;
    const short* kbp = (const short*)kb;
    const short* vtp = (const short*)vt;

    __shared__ short Ks[2][64 * 64];   // [buf][kv-row][d]    16 KB
    __shared__ short Vs[2][64 * 64];   // [buf][d-row][kv]    16 KB
    __shared__ short p_s[4][16][72];   // per-wave P tile      9 KB

    #pragma unroll
    for (int phase = 0; phase < 2; ++phase) {
        const int qt = (phase == 0) ? bx : (15 - bx);
        const int q0 = qt * 64 + w * 16;

        short8v aq0, aq1;
        {
            const short* qp = (const short*)qb + (headRow + q0 + lc) * 64 + lg * 8;
            aq0 = *(const short8v*)(qp);
            aq1 = *(const short8v*)(qp + 32);
        }

        float m_r[4], l_r[4];
        f32x4 o_acc[4];
        #pragma unroll
        for (int r = 0; r < 4; ++r) { m_r[r] = -1e30f; l_r[r] = 0.0f; }
        #pragma unroll
        for (int n = 0; n < 4; ++n) o_acc[n] = (f32x4){0.f, 0.f, 0.f, 0.f};

        // prologue: stage KV tile 0 into buf 0 (cooperative, once per block)
        #pragma unroll
        for (int u = 0; u < 2; ++u) {
            const int t = u * 256 + tid;
            const int row = t >> 3, c8 = (t & 7) * 8;
            gload16(kbp + (headRow + row) * 64 + c8, &Ks[0][t * 8]);
            gload16(vtp + (vtRow + row) * T_ + c8, &Vs[0][t * 8]);
        }
        __syncthreads();

        int cur = 0;
        for (int kt = 0; kt <= qt; ++kt) {
            // issue next tile's staging loads (latency hides under compute)
            if (kt < qt) {
                const int kv1 = (kt + 1) * 64;
                #pragma unroll
                for (int u = 0; u < 2; ++u) {
                    const int t = u * 256 + tid;
                    const int row = t >> 3, c8 = (t & 7) * 8;
                    gload16(kbp + (headRow + kv1 + row) * 64 + c8, &Ks[cur ^ 1][t * 8]);
                    gload16(vtp + (vtRow + row) * T_ + kv1 + c8, &Vs[cur ^ 1][t * 8]);
                }
            }
            const short* Kc = Ks[cur];
            const short* Vc = Vs[cur];

            // QK^T from LDS
            f32x4 s[4];
            #pragma unroll
            for (int n = 0; n < 4; ++n) {
                const short8v bk0 = *(const short8v*)(Kc + (n * 16 + lc) * 64 + lg * 8);
                const short8v bk1 = *(const short8v*)(Kc + (n * 16 + lc) * 64 + 32 + lg * 8);
                f32x4 a2 = (f32x4){0.f, 0.f, 0.f, 0.f};
                a2 = __builtin_amdgcn_mfma_f32_16x16x32_bf16(aq0, bk0, a2, 0, 0, 0);
                a2 = __builtin_amdgcn_mfma_f32_16x16x32_bf16(aq1, bk1, a2, 0, 0, 0);
                s[n] = a2;
            }

            if (kt == qt) {   // diagonal tile: causal mask
                const int kv0 = kt * 64;
                #pragma unroll
                for (int n = 0; n < 4; ++n) {
                    const int kvg = kv0 + n * 16 + lc;
                    #pragma unroll
                    for (int r = 0; r < 4; ++r) {
                        const int qg = q0 + lg * 4 + r;
                        if (kvg > qg) s[n][r] = -1e30f;
                    }
                }
            }

            // online softmax (rows r in regs; cols across 16-lane group)
            float p[4][4];
            float pscale[4];
            #pragma unroll
            for (int r = 0; r < 4; ++r) {
                float tm = fmaxf(fmaxf(s[0][r], s[1][r]), fmaxf(s[2][r], s[3][r]));
                #pragma unroll
                for (int mk = 8; mk >= 1; mk >>= 1) tm = fmaxf(tm, __shfl_xor(tm, mk, 16));
                const float mnew = fmaxf(m_r[r], tm);
                pscale[r] = __expf(m_r[r] - mnew);
                float ps = 0.f;
                #pragma unroll
                for (int n = 0; n < 4; ++n) { p[n][r] = __expf(s[n][r] - mnew); ps += p[n][r]; }
                #pragma unroll
                for (int mk = 8; mk >= 1; mk >>= 1) ps += __shfl_xor(ps, mk, 16);
                l_r[r] = l_r[r] * pscale[r] + ps;
                m_r[r] = mnew;
            }
            #pragma unroll
            for (int n = 0; n < 4; ++n)
                #pragma unroll
                for (int r = 0; r < 4; ++r) o_acc[n][r] *= pscale[r];

            // P -> per-wave LDS tile (intra-wave ordering only)
            #pragma unroll
            for (int n = 0; n < 4; ++n)
                #pragma unroll
                for (int r = 0; r < 4; ++r)
                    p_s[w][lg * 4 + r][n * 16 + lc] = f2bf(p[n][r]);

            const short* prow = &p_s[w][lc][lg * 8];
            const short8v pa0 = *(const short8v*)(prow);
            const short8v pa1 = *(const short8v*)(prow + 32);

            // PV from LDS
            #pragma unroll
            for (int n = 0; n < 4; ++n) {
                const short8v bv0 = *(const short8v*)(Vc + (n * 16 + lc) * 64 + lg * 8);
                const short8v bv1 = *(const short8v*)(Vc + (n * 16 + lc) * 64 + 32 + lg * 8);
                o_acc[n] = __builtin_amdgcn_mfma_f32_16x16x32_bf16(pa0, bv0, o_acc[n], 0, 0, 0);
                o_acc[n] = __builtin_amdgcn_mfma_f32_16x16x32_bf16(pa1, bv1, o_acc[n], 0, 0, 0);
            }

            __syncthreads();   // next tile staged + all reads of cur done
            cur ^= 1;
        }

        #pragma unroll
        for (int r = 0; r < 4; ++r) {
            const float inv = 1.0f / l_r[r];
            const int q = q0 + lg * 4 + r;
            short* op = ab + ((size_t)(b * T_) + q) * C_ + h * 64 + lc;
            #pragma unroll
            for (int n = 0; n < 4; ++n) op[n * 16] = f2bf(o_acc[n][r] * inv);
        }
    }
}

// ---------------------------------------------------------------------------

extern "C" void kernel_launch(void* const* d_in, const int* in_sizes, int n_in,
                              void* d_out, int out_size, void* d_ws, size_t ws_size,
                              hipStream_t stream)
{
    const float* x  = (const float*)d_in[0];
    const float* Wq = (const float*)d_in[1];
    const float* Wk = (const float*)d_in[2];
    const float* Wv = (const float*)d_in[3];
    const float* Wp = (const float*)d_in[4];
    const float* bp = (const float*)d_in[5];
    float* out = (float*)d_out;

    char* ws = (char*)d_ws;
    const size_t NE = (size_t)B_ * T_ * C_;          // 6,291,456
    const size_t BF = NE * sizeof(short);            // 12.58 MB
    short* xb  = (short*)(ws);
    short* qb  = (short*)(ws + BF);
    short* kb  = (short*)(ws + 2 * BF);
    short* vb  = (short*)(ws + 3 * BF);
    short* vt  = (short*)(ws + 4 * BF);
    short* ab  = (short*)(ws + 5 * BF);
    short* wt  = (short*)(ws + 6 * BF);                       // 3 x 768 x 768 bf16
    short* wpt = (short*)(ws + 6 * BF + 3 * C_ * C_ * 2);     // 768 x 768 bf16

    // prep: conversions + weight transposes
    x_to_bf16<<<dim3(NE / (256 * 8)), dim3(256), 0, stream>>>(x, xb);
    w_transpose<<<dim3(12, 12, 3), dim3(256), 0, stream>>>(Wq, Wk, Wv, wt);
    wp_transpose<<<dim3(12, 12), dim3(256), 0, stream>>>(Wp, wpt);

    // 1) QKV projections (MFMA) -> bf16 [B,H,T,64]
    qkv_mfma<<<dim3(C_ / BN, (B_ * T_) / BM, 3), dim3(256), 0, stream>>>(
        xb, wt, qb, kb, vb);

    // 2) V transpose -> [B,H,64,T]
    v_transpose<<<dim3(T_ / 64, H_, B_), dim3(256), 0, stream>>>(
        (const __hip_bfloat16*)vb, (__hip_bfloat16*)vt);

    // 3) causal flash attention (MFMA, LDS-staged, XCD-swizzled) -> ab bf16
    attn_mfma<<<dim3(8 * H_ * B_), dim3(256), 0, stream>>>(
        (const __hip_bfloat16*)qb, (const __hip_bfloat16*)kb,
        (const __hip_bfloat16*)vt, ab);

    // 4) output projection (MFMA) + bias -> d_out fp32
    proj_mfma<<<dim3(C_ / BN, (B_ * T_) / BM), dim3(256), 0, stream>>>(
        ab, wpt, bp, out);
}